// Round 1
// baseline (46266.058 us; speedup 1.0000x reference)
//
#include <hip/hip_runtime.h>

// Problem constants
constexpr int B_   = 32;
constexpr int S_   = 512;
constexpr int T_   = 512;
constexpr int ENC_ = 512;
constexpr int ATT_ = 128;
constexpr int PO_  = 256;
constexpr int DEC_ = 1024;
constexpr int M_   = 128;
constexpr int G3_  = 3072;   // 3*DEC

// Output offsets (floats)
constexpr int MEL_OFF  = 0;
constexpr int STOP_OFF = B_*T_*M_;            // 2,097,152
constexpr int AW_OFF   = STOP_OFF + B_*T_;    // 2,113,536

__device__ __forceinline__ float frcp(float x){ return __builtin_amdgcn_rcpf(x); }
__device__ __forceinline__ float ftanh(float x){
    float e = __expf(2.0f*x);               // +inf / 0 saturate correctly
    return 1.0f - 2.0f*frcp(e + 1.0f);
}
__device__ __forceinline__ float fsig(float x){ return frcp(1.0f + __expf(-x)); }

// ---------------- prep: tiled transpose src[R][C] -> dst[C][R] ----------------
__global__ __launch_bounds__(128) void k_transpose(const float* __restrict__ src,
                                                   float* __restrict__ dst,
                                                   int R, int C){
    __shared__ float tile[32][33];
    int tC = C >> 5;
    int tr = blockIdx.x / tC, tc = blockIdx.x % tC;
    int r0 = tr << 5, c0 = tc << 5;
    int lr = threadIdx.x >> 5, lc = threadIdx.x & 31;
    #pragma unroll
    for (int i = 0; i < 8; i++){
        int r = (i << 2) + lr;
        tile[r][lc] = src[(size_t)(r0 + r)*C + c0 + lc];
    }
    __syncthreads();
    #pragma unroll
    for (int i = 0; i < 8; i++){
        int r = (i << 2) + lr;
        dst[(size_t)(c0 + r)*R + r0 + lc] = tile[lc][r];
    }
}

// ---------------- prep: ep_t[b][a][s] = (enc @ att_we + be) transposed --------
__global__ __launch_bounds__(128) void k_encproj(const float* __restrict__ enc,
        const float* __restrict__ we, const float* __restrict__ be,
        float* __restrict__ ep_t){
    __shared__ float wel[64*128];
    __shared__ float encl[32*69];
    int b = blockIdx.x >> 4, s0 = (blockIdx.x & 15) << 5;
    int tid = threadIdx.x;
    int sl = tid & 31, ag = tid >> 5;        // ag 0..3 -> 32 a's each
    float acc[32];
    #pragma unroll
    for (int i = 0; i < 32; i++) acc[i] = 0.f;
    for (int k0 = 0; k0 < ENC_; k0 += 64){
        __syncthreads();
        for (int p = 0; p < 64; p++){
            int idx = tid + (p << 7);
            wel[idx] = we[(size_t)(k0 + (idx >> 7))*ATT_ + (idx & 127)];
        }
        for (int p = 0; p < 16; p++){
            int idx = tid + (p << 7);
            int kk = idx & 63, ss = idx >> 6;
            encl[ss*69 + kk] = enc[((size_t)b*S_ + s0 + ss)*ENC_ + k0 + kk];
        }
        __syncthreads();
        for (int kk = 0; kk < 64; kk++){
            float ev = encl[sl*69 + kk];
            const float* wr = &wel[(kk << 7) + (ag << 5)];
            #pragma unroll
            for (int j = 0; j < 32; j++) acc[j] += ev * wr[j];
        }
    }
    #pragma unroll
    for (int j = 0; j < 32; j++){
        int a = (ag << 5) + j;
        ep_t[((size_t)b*ATT_ + a)*S_ + s0 + sl] = acc[j] + be[a];
    }
}

// ---------------- prep: X_all[t][b][:] = PreNet(prev_mel) ---------------------
__global__ __launch_bounds__(128) void k_prenet(const float* __restrict__ tm,
        const float* __restrict__ w1, const float* __restrict__ b1,
        const float* __restrict__ w2, const float* __restrict__ b2,
        float* __restrict__ xall){
    __shared__ float mel_l[128*20];
    __shared__ float h1_l[256*20];
    int row0 = blockIdx.x << 4;              // 16 rows per block, same t
    int t = row0 >> 5, b0 = row0 & 31;
    int tid = threadIdx.x;
    for (int p = 0; p < 16; p++){
        int idx = tid + (p << 7);
        int k = idx & 127, r = idx >> 7;
        float v = 0.f;
        if (t > 0) v = tm[((size_t)(b0 + r)*T_ + (t - 1))*M_ + k];
        mel_l[k*20 + r] = v;
    }
    __syncthreads();
    float acc1[16], acc2[16];
    #pragma unroll
    for (int i = 0; i < 16; i++){ acc1[i] = 0.f; acc2[i] = 0.f; }
    for (int k = 0; k < M_; k++){
        float wa = w1[k*256 + tid];
        float wb = w1[k*256 + tid + 128];
        float mv[16];
        *(float4*)&mv[0]  = *(const float4*)&mel_l[k*20 + 0];
        *(float4*)&mv[4]  = *(const float4*)&mel_l[k*20 + 4];
        *(float4*)&mv[8]  = *(const float4*)&mel_l[k*20 + 8];
        *(float4*)&mv[12] = *(const float4*)&mel_l[k*20 + 12];
        #pragma unroll
        for (int r = 0; r < 16; r++){ acc1[r] += mv[r]*wa; acc2[r] += mv[r]*wb; }
    }
    float bb1a = b1[tid], bb1b = b1[tid + 128];
    #pragma unroll
    for (int r = 0; r < 16; r++){
        h1_l[tid*20 + r]         = fmaxf(acc1[r] + bb1a, 0.f);
        h1_l[(tid + 128)*20 + r] = fmaxf(acc2[r] + bb1b, 0.f);
    }
    __syncthreads();
    #pragma unroll
    for (int i = 0; i < 16; i++){ acc1[i] = 0.f; acc2[i] = 0.f; }
    for (int k = 0; k < 256; k++){
        float wa = w2[k*256 + tid];
        float wb = w2[k*256 + tid + 128];
        float mv[16];
        *(float4*)&mv[0]  = *(const float4*)&h1_l[k*20 + 0];
        *(float4*)&mv[4]  = *(const float4*)&h1_l[k*20 + 4];
        *(float4*)&mv[8]  = *(const float4*)&h1_l[k*20 + 8];
        *(float4*)&mv[12] = *(const float4*)&h1_l[k*20 + 12];
        #pragma unroll
        for (int r = 0; r < 16; r++){ acc1[r] += mv[r]*wa; acc2[r] += mv[r]*wb; }
    }
    float bb2a = b2[tid], bb2b = b2[tid + 128];
    #pragma unroll
    for (int r = 0; r < 16; r++){
        xall[((size_t)row0 + r)*PO_ + tid]       = fmaxf(acc1[r] + bb2a, 0.f);
        xall[((size_t)row0 + r)*PO_ + tid + 128] = fmaxf(acc2[r] + bb2b, 0.f);
    }
}

// ---------------- step phase A: gh partials | scores | mel(t-1) | gi_x --------
__global__ __launch_bounds__(128) void k_stepA(
        const float* __restrict__ wg_t, const float* __restrict__ wi_t,
        const float* __restrict__ ep_t, const float* __restrict__ xall,
        const float* __restrict__ h_prev,
        const float* __restrict__ dpp, const float* __restrict__ bd,
        const float* __restrict__ vvec, const float* __restrict__ vb,
        const float* __restrict__ ctxp, const float* __restrict__ denp,
        const float* __restrict__ ow, const float* __restrict__ ob,
        const float* __restrict__ sw, const float* __restrict__ sb,
        float* __restrict__ ghp, float* __restrict__ gixp,
        float* __restrict__ es, float* __restrict__ out, int t){
    __shared__ float smem[8448];
    int blk = blockIdx.x, tid = threadIdx.x;
    if (blk < 256){
        // ---- gh partial: panel p (96 j), k-slice ks (128 k) ----
        if (t >= T_) return;
        int p = blk >> 3, ks = blk & 7;
        int j0 = p*96, k0 = ks << 7;
        float* ht = smem;           // [64][36]
        float* wt = smem + 2304;    // [64][96]
        float acc[4][6];
        #pragma unroll
        for (int i = 0; i < 4; i++)
            #pragma unroll
            for (int j = 0; j < 6; j++) acc[i][j] = 0.f;
        int tb = tid >> 4, tj = tid & 15;
        for (int kc = 0; kc < 2; kc++){
            int kb = k0 + (kc << 6);
            __syncthreads();
            for (int p2 = 0; p2 < 48; p2++){
                int idx = tid + (p2 << 7);
                int r = idx / 96, c = idx - r*96;
                wt[r*96 + c] = wg_t[(size_t)(kb + r)*G3_ + j0 + c];
            }
            for (int p2 = 0; p2 < 16; p2++){
                int idx = tid + (p2 << 7);
                int kk = idx & 63, bb2 = idx >> 6;
                ht[kk*36 + bb2] = h_prev[(bb2 << 10) + kb + kk];
            }
            __syncthreads();
            for (int kk = 0; kk < 64; kk++){
                float hv[4];
                *(float4*)hv = *(const float4*)(ht + kk*36 + (tb << 2));
                const float* wr = wt + kk*96 + tj*6;
                float wv[6];
                *(float2*)&wv[0] = *(const float2*)(wr);
                *(float2*)&wv[2] = *(const float2*)(wr + 2);
                *(float2*)&wv[4] = *(const float2*)(wr + 4);
                #pragma unroll
                for (int i = 0; i < 4; i++)
                    #pragma unroll
                    for (int j = 0; j < 6; j++) acc[i][j] += hv[i]*wv[j];
            }
        }
        int b0 = tb << 2;
        #pragma unroll
        for (int i = 0; i < 4; i++)
            #pragma unroll
            for (int j = 0; j < 6; j++)
                ghp[((size_t)(ks << 5) + b0 + i)*G3_ + j0 + tj*6 + j] = acc[i][j];
    } else if (blk < 384){
        // ---- scores + exp (max-free softmax numerator) ----
        if (t >= T_) return;
        int i = blk - 256;
        int b = i >> 2, q = i & 3;
        float* dpl = smem; float* vl = smem + 128;
        float dp = bd[tid];
        #pragma unroll
        for (int dc = 0; dc < 8; dc++) dp += dpp[((dc << 5) + b)*ATT_ + tid];
        dpl[tid] = dp;
        vl[tid]  = vvec[tid];
        __syncthreads();
        int s = (q << 7) + tid;
        const float* epb = ep_t + (size_t)b*ATT_*S_;
        float sc = vb[0];
        #pragma unroll 4
        for (int a = 0; a < 128; a++)
            sc += ftanh(epb[(a << 9) + s] + dpl[a]) * vl[a];
        es[(b << 9) + s] = __expf(sc);
    } else if (blk < 448){
        // ---- mel/stop for step t-1 ----
        if (t == 0) return;
        int i = blk - 384;
        int b = i >> 1, jh = i & 1;
        float* doutl = smem; float* red = smem + 1536;
        float den = 0.f;
        #pragma unroll
        for (int sp = 0; sp < 8; sp++) den += denp[(sp << 5) + b];
        float rden = frcp(den);
        for (int i2 = tid; i2 < 1536; i2 += 128){
            float v;
            if (i2 < 1024) v = h_prev[(b << 10) + i2];
            else {
                int e = i2 - 1024; float c = 0.f;
                #pragma unroll
                for (int sp = 0; sp < 8; sp++) c += ctxp[((sp << 5) + b)*ENC_ + e];
                v = c*rden;
            }
            doutl[i2] = v;
        }
        __syncthreads();
        int jl = tid & 63, kh = tid >> 6;
        int j = (jh << 6) + jl;
        float a = 0.f;
        int kbase = kh*768;
        #pragma unroll 4
        for (int k = 0; k < 768; k++) a += doutl[kbase + k]*ow[(size_t)(kbase + k)*M_ + j];
        red[(kh << 6) + jl] = a;
        __syncthreads();
        if (kh == 0)
            out[MEL_OFF + ((size_t)b*T_ + t - 1)*M_ + j] = red[jl] + red[64 + jl] + ob[j];
        __syncthreads();
        float sp_ = 0.f;
        for (int i2 = tid; i2 < 1536; i2 += 128) sp_ += doutl[i2]*sw[i2];
        red[tid] = sp_;
        __syncthreads();
        for (int off = 64; off > 0; off >>= 1){
            if (tid < off) red[tid] += red[tid + off];
            __syncthreads();
        }
        if (tid == 0 && jh == 0) out[STOP_OFF + b*T_ + t - 1] = red[0] + sb[0];
    } else {
        // ---- gi_x partial: x-part of GRU input GEMM ----
        if (t >= T_) return;
        int i = blk - 448;
        int p = i >> 2, ks = i & 3;
        int j0 = p << 6, k0 = ks << 6;
        float* xt = smem;          // [64][36]
        float* wt = smem + 2304;   // [64][64]
        for (int p2 = 0; p2 < 32; p2++){
            int idx = tid + (p2 << 7);
            wt[idx] = wi_t[(size_t)(k0 + (idx >> 6))*G3_ + j0 + (idx & 63)];
        }
        for (int p2 = 0; p2 < 16; p2++){
            int idx = tid + (p2 << 7);
            int kk = idx & 63, bb2 = idx >> 6;
            xt[kk*36 + bb2] = xall[((size_t)(t << 5) + bb2)*PO_ + k0 + kk];
        }
        __syncthreads();
        int tb = tid >> 4, tj = tid & 15;
        float acc[4][4];
        #pragma unroll
        for (int i2 = 0; i2 < 4; i2++)
            #pragma unroll
            for (int j2 = 0; j2 < 4; j2++) acc[i2][j2] = 0.f;
        for (int kk = 0; kk < 64; kk++){
            float xv[4], wv[4];
            *(float4*)xv = *(const float4*)(xt + kk*36 + (tb << 2));
            *(float4*)wv = *(const float4*)(wt + (kk << 6) + (tj << 2));
            #pragma unroll
            for (int i2 = 0; i2 < 4; i2++)
                #pragma unroll
                for (int j2 = 0; j2 < 4; j2++) acc[i2][j2] += xv[i2]*wv[j2];
        }
        int b0 = tb << 2;
        #pragma unroll
        for (int i2 = 0; i2 < 4; i2++)
            #pragma unroll
            for (int j2 = 0; j2 < 4; j2++)
                gixp[((size_t)(ks << 5) + b0 + i2)*G3_ + j0 + (tj << 2) + j2] = acc[i2][j2];
    }
}

// ---------------- step phase B: context partials + denom ----------------------
__global__ __launch_bounds__(128) void k_stepB(const float* __restrict__ enc,
        const float* __restrict__ es, float* __restrict__ ctxp,
        float* __restrict__ denp){
    __shared__ float esl[64];
    int b = blockIdx.x >> 3, sp = blockIdx.x & 7;
    int s0 = sp << 6, tid = threadIdx.x;
    if (tid < 64) esl[tid] = es[(b << 9) + s0 + tid];
    __syncthreads();
    float4 acc = make_float4(0.f, 0.f, 0.f, 0.f);
    const float* encb = enc + ((size_t)(b << 9) + s0)*ENC_;
    int e4 = tid << 2;
    for (int s = 0; s < 64; s++){
        float ev = esl[s];
        float4 x = *(const float4*)(encb + (size_t)s*ENC_ + e4);
        acc.x += ev*x.x; acc.y += ev*x.y; acc.z += ev*x.z; acc.w += ev*x.w;
    }
    *(float4*)(ctxp + ((size_t)(sp << 5) + b)*ENC_ + e4) = acc;
    if (tid == 0){
        float d = 0.f;
        for (int s = 0; s < 64; s++) d += esl[s];
        denp[(sp << 5) + b] = d;
    }
}

// ---------------- step phase C: gi_ctx partials + aw write --------------------
__global__ __launch_bounds__(128) void k_stepC(const float* __restrict__ wi_t,
        const float* __restrict__ ctxp, const float* __restrict__ denp,
        const float* __restrict__ es, float* __restrict__ gicp,
        float* __restrict__ out, int t){
    __shared__ float smem[32 + 2304 + 4096];
    int blk = blockIdx.x, tid = threadIdx.x;
    if (blk < 384){
        float* rd = smem; float* ct = smem + 32; float* wt = smem + 32 + 2304;
        int p = blk >> 3, ks = blk & 7;
        int j0 = p << 6, e0 = ks << 6;
        if (tid < 32){
            float d = 0.f;
            #pragma unroll
            for (int sp = 0; sp < 8; sp++) d += denp[(sp << 5) + tid];
            rd[tid] = frcp(d);
        }
        __syncthreads();
        for (int p2 = 0; p2 < 16; p2++){
            int idx = tid + (p2 << 7);
            int ee = idx & 63, bb2 = idx >> 6;
            float c = 0.f;
            #pragma unroll
            for (int sp = 0; sp < 8; sp++) c += ctxp[((sp << 5) + bb2)*ENC_ + e0 + ee];
            ct[ee*36 + bb2] = c * rd[bb2];
        }
        for (int p2 = 0; p2 < 32; p2++){
            int idx = tid + (p2 << 7);
            wt[idx] = wi_t[(size_t)(256 + e0 + (idx >> 6))*G3_ + j0 + (idx & 63)];
        }
        __syncthreads();
        int tb = tid >> 4, tj = tid & 15;
        float acc[4][4];
        #pragma unroll
        for (int i2 = 0; i2 < 4; i2++)
            #pragma unroll
            for (int j2 = 0; j2 < 4; j2++) acc[i2][j2] = 0.f;
        for (int kk = 0; kk < 64; kk++){
            float xv[4], wv[4];
            *(float4*)xv = *(const float4*)(ct + kk*36 + (tb << 2));
            *(float4*)wv = *(const float4*)(wt + (kk << 6) + (tj << 2));
            #pragma unroll
            for (int i2 = 0; i2 < 4; i2++)
                #pragma unroll
                for (int j2 = 0; j2 < 4; j2++) acc[i2][j2] += xv[i2]*wv[j2];
        }
        int b0 = tb << 2;
        #pragma unroll
        for (int i2 = 0; i2 < 4; i2++)
            #pragma unroll
            for (int j2 = 0; j2 < 4; j2++)
                gicp[((size_t)(ks << 5) + b0 + i2)*G3_ + j0 + (tj << 2) + j2] = acc[i2][j2];
    } else {
        int b = blk - 384;
        float den = 0.f;
        #pragma unroll
        for (int sp = 0; sp < 8; sp++) den += denp[(sp << 5) + b];
        float rden = frcp(den);
        int s4 = tid << 2;
        float4 ev = *(const float4*)(es + (b << 9) + s4);
        float4 r;
        r.x = ev.x*rden; r.y = ev.y*rden; r.z = ev.z*rden; r.w = ev.w*rden;
        *(float4*)(out + AW_OFF + ((size_t)b*T_ + t)*S_ + s4) = r;
    }
}

// ---------------- step phase D: gates -> h(t), dproj partials -----------------
__global__ __launch_bounds__(128) void k_stepD(
        const float* __restrict__ gixp, const float* __restrict__ gicp,
        const float* __restrict__ ghp, const float* __restrict__ bih,
        const float* __restrict__ bhh, const float* __restrict__ h_prev,
        const float* __restrict__ wd, float* __restrict__ h_next,
        float* __restrict__ dpp){
    __shared__ float hl[128];
    int b = blockIdx.x >> 3, dc = blockIdx.x & 7;
    int tid = threadIdx.x;
    int d = (dc << 7) + tid;
    float gir = bih[d], giz = bih[1024 + d], gin = bih[2048 + d];
    #pragma unroll
    for (int ks = 0; ks < 4; ks++){
        const float* g = gixp + ((size_t)(ks << 5) + b)*G3_;
        gir += g[d]; giz += g[1024 + d]; gin += g[2048 + d];
    }
    #pragma unroll
    for (int ks = 0; ks < 8; ks++){
        const float* g = gicp + ((size_t)(ks << 5) + b)*G3_;
        gir += g[d]; giz += g[1024 + d]; gin += g[2048 + d];
    }
    float ghr = bhh[d], ghz = bhh[1024 + d], ghn = bhh[2048 + d];
    #pragma unroll
    for (int ks = 0; ks < 8; ks++){
        const float* g = ghp + ((size_t)(ks << 5) + b)*G3_;
        ghr += g[d]; ghz += g[1024 + d]; ghn += g[2048 + d];
    }
    float r = fsig(gir + ghr);
    float z = fsig(giz + ghz);
    float n = ftanh(gin + r*ghn);
    float hv = (1.f - z)*n + z*h_prev[(b << 10) + d];
    h_next[(b << 10) + d] = hv;
    hl[tid] = hv;
    __syncthreads();
    float dpa = 0.f;
    int dbase = dc << 7;
    #pragma unroll 4
    for (int dd = 0; dd < 128; dd++) dpa += hl[dd]*wd[(size_t)(dbase + dd)*ATT_ + tid];
    dpp[((size_t)(dc << 5) + b)*ATT_ + tid] = dpa;
}

extern "C" void kernel_launch(void* const* d_in, const int* in_sizes, int n_in,
                              void* d_out, int out_size, void* d_ws, size_t ws_size,
                              hipStream_t stream){
    const float* enc = (const float*)d_in[0];
    const float* tm  = (const float*)d_in[1];
    const float* pw1 = (const float*)d_in[2];
    const float* pb1 = (const float*)d_in[3];
    const float* pw2 = (const float*)d_in[4];
    const float* pb2 = (const float*)d_in[5];
    const float* awe = (const float*)d_in[6];
    const float* abe = (const float*)d_in[7];
    const float* awd = (const float*)d_in[8];
    const float* abd = (const float*)d_in[9];
    const float* av  = (const float*)d_in[10];
    const float* avb = (const float*)d_in[11];
    const float* wih = (const float*)d_in[12];
    const float* whh = (const float*)d_in[13];
    const float* bih = (const float*)d_in[14];
    const float* bhh = (const float*)d_in[15];
    const float* oww = (const float*)d_in[16];
    const float* obb = (const float*)d_in[17];
    const float* sww = (const float*)d_in[18];
    const float* sbb = (const float*)d_in[19];
    float* out = (float*)d_out;
    float* ws  = (float*)d_ws;

    // workspace layout (floats) — total ~56.0 MB
    float* ep_t = ws;                  // [B][ATT][S]      2,097,152
    float* xall = ep_t + 2097152;      // [T][B][PO]       4,194,304
    float* wg_t = xall + 4194304;      // [DEC][3DEC]      3,145,728
    float* wi_t = wg_t + 3145728;      // [768][3DEC]      2,359,296
    float* hbuf = wi_t + 2359296;      // [2][B][DEC]         65,536
    float* ghp  = hbuf + 65536;        // [8][B][3DEC]       786,432
    float* gixp = ghp + 786432;        // [4][B][3DEC]       393,216
    float* gicp = gixp + 393216;       // [8][B][3DEC]       786,432
    float* es   = gicp + 786432;       // [B][S]              16,384
    float* denp = es + 16384;          // [8][B]                 256
    float* ctxp = denp + 256;          // [8][B][ENC]        131,072
    float* dpp  = ctxp + 131072;       // [8][B][ATT]         32,768

    hipMemsetAsync(hbuf, 0, (size_t)65536*sizeof(float), stream);
    hipMemsetAsync(dpp, 0, (size_t)32768*sizeof(float), stream);

    k_transpose<<<3072, 128, 0, stream>>>(whh, wg_t, G3_, DEC_);
    k_transpose<<<2304, 128, 0, stream>>>(wih, wi_t, G3_, 768);
    k_encproj<<<512, 128, 0, stream>>>(enc, awe, abe, ep_t);
    k_prenet<<<1024, 128, 0, stream>>>(tm, pw1, pb1, pw2, pb2, xall);

    for (int t = 0; t <= T_; t++){
        const float* h_prev = hbuf + (size_t)(t & 1)*32768;
        float* h_next = hbuf + (size_t)((t & 1) ^ 1)*32768;
        k_stepA<<<640, 128, 0, stream>>>(wg_t, wi_t, ep_t, xall, h_prev, dpp, abd,
                                         av, avb, ctxp, denp, oww, obb, sww, sbb,
                                         ghp, gixp, es, out, t);
        if (t < T_){
            k_stepB<<<256, 128, 0, stream>>>(enc, es, ctxp, denp);
            k_stepC<<<416, 128, 0, stream>>>(wi_t, ctxp, denp, es, gicp, out, t);
            k_stepD<<<256, 128, 0, stream>>>(gixp, gicp, ghp, bih, bhh, h_prev, awd,
                                             h_next, dpp);
        }
    }
}